// Round 1
// baseline (555.901 us; speedup 1.0000x reference)
//
#include <hip/hip_runtime.h>
#include <hip/hip_bf16.h>

// SkipGCN: out = gcn(relu(gcn(x,W1,b1)),W2,b2) + x@Ws + bs
// N=100000 nodes, E=1600000 edges, in=165, hid=128, out=2, all fp32.
//
// Pipeline (all on `stream`, capture-safe):
//  0. memset cnt=0
//  1. detect edge dtype (int32 vs int64) -> flag in ws
//  2. count in-degree per dst (atomicAdd int)
//  3. dinv[i] = rsqrt(1+cnt[i])          (self-loop included)
//  4. exclusive scan cnt -> row_ptr (3 kernels), cursor=row_ptr
//  5. fill CSR col_src by dst (atomic cursor)
//  6. gemm1: h = x@W1                     [N,128]
//  7. skip:  skip = x@Ws + bs + b2        [N,2]   (b2 folded in)
//  8. agg1:  wave-per-node: sum norm*h[src] (+self), relu(+b1),
//            fused h2 = h1@W2 via cross-lane reduce   [N,2]
//  9. agg2:  thread-per-node: out = sum norm*h2[src] (+self) + skip

#define NN 100000
#define EE 1600000
#define IND 165
#define HID 128

__global__ void detect_kernel(const int* e32, int* flag) {
    // if edges are int64, the high 32-bit word of every value is 0
    // (values < 100000). Check odd int32 words of first 256 entries.
    __shared__ int nz;
    if (threadIdx.x == 0) nz = 0;
    __syncthreads();
    if (e32[2 * threadIdx.x + 1] != 0) atomicOr(&nz, 1);
    __syncthreads();
    if (threadIdx.x == 0) flag[0] = (nz == 0) ? 1 : 0;  // 1 => int64 layout
}

__global__ void count_kernel(const int* e32, const int* flag, int* cnt, int E) {
    int e = blockIdx.x * blockDim.x + threadIdx.x;
    if (e >= E) return;
    int f = flag[0];
    int dst = f ? e32[2 * (E + e)] : e32[E + e];
    atomicAdd(&cnt[dst], 1);
}

__global__ void dinv_kernel(const int* cnt, float* dinv, int n) {
    int i = blockIdx.x * blockDim.x + threadIdx.x;
    if (i < n) dinv[i] = rsqrtf(1.0f + (float)cnt[i]);
}

// ---- exclusive scan over cnt[n] -> pref[n], block=256, 8 items/thread ----
__global__ __launch_bounds__(256) void scan1_kernel(const int* cnt, int* pref, int* bsum, int n) {
    __shared__ int sdata[256];
    int base = blockIdx.x * 2048 + threadIdx.x * 8;
    int v[8];
    int s = 0;
    #pragma unroll
    for (int j = 0; j < 8; ++j) {
        int idx = base + j;
        int t = (idx < n) ? cnt[idx] : 0;
        v[j] = s;          // exclusive within thread
        s += t;
    }
    sdata[threadIdx.x] = s;
    __syncthreads();
    for (int off = 1; off < 256; off <<= 1) {
        int t = (threadIdx.x >= off) ? sdata[threadIdx.x - off] : 0;
        __syncthreads();
        sdata[threadIdx.x] += t;
        __syncthreads();
    }
    int excl = (threadIdx.x == 0) ? 0 : sdata[threadIdx.x - 1];
    if (threadIdx.x == 255) bsum[blockIdx.x] = sdata[255];
    #pragma unroll
    for (int j = 0; j < 8; ++j) {
        int idx = base + j;
        if (idx < n) pref[idx] = excl + v[j];
    }
}

__global__ void scan2_kernel(int* bsum, int g) {
    if (threadIdx.x == 0) {
        int run = 0;
        for (int j = 0; j < g; ++j) { int t = bsum[j]; bsum[j] = run; run += t; }
    }
}

__global__ void scan3_kernel(int* pref, const int* bsum, int* cursor, int n, int total) {
    int i = blockIdx.x * blockDim.x + threadIdx.x;
    if (i < n) {
        int v = pref[i] + bsum[i >> 11];
        pref[i] = v;
        cursor[i] = v;
    }
    if (i == 0) pref[n] = total;
}

__global__ void fill_kernel(const int* e32, const int* flag, int* cursor, int* col_src, int E) {
    int e = blockIdx.x * blockDim.x + threadIdx.x;
    if (e >= E) return;
    int f = flag[0];
    int src = f ? e32[2 * e] : e32[e];
    int dst = f ? e32[2 * (E + e)] : e32[E + e];
    int p = atomicAdd(&cursor[dst], 1);
    col_src[p] = src;
}

// ---- h = x @ W1   (x: [N,165], W1: [165,128]) — 8 rows/block, 128 thr ----
#define RB 8
__global__ __launch_bounds__(128) void gemm1_kernel(const float* __restrict__ x,
                                                    const float* __restrict__ W1,
                                                    float* __restrict__ h) {
    __shared__ float xs[RB * IND];
    int row0 = blockIdx.x * RB;
    const float* xg = x + (size_t)row0 * IND;
    for (int t = threadIdx.x; t < RB * IND; t += 128) xs[t] = xg[t];
    __syncthreads();
    int c = threadIdx.x;
    float acc[RB];
    #pragma unroll
    for (int r = 0; r < RB; ++r) acc[r] = 0.f;
    for (int k = 0; k < IND; ++k) {
        float w = W1[k * HID + c];
        #pragma unroll
        for (int r = 0; r < RB; ++r) acc[r] = fmaf(xs[r * IND + k], w, acc[r]);
    }
    #pragma unroll
    for (int r = 0; r < RB; ++r) h[(size_t)(row0 + r) * HID + c] = acc[r];
}

// ---- skip = x @ Ws + bs + b2 — one wave per row ----
__global__ __launch_bounds__(256) void skip_kernel(const float* __restrict__ x,
                                                   const float* __restrict__ Ws,
                                                   const float* __restrict__ bs,
                                                   const float* __restrict__ b2,
                                                   float* __restrict__ skip, int n) {
    int wid = threadIdx.x >> 6, lane = threadIdx.x & 63;
    int row = blockIdx.x * 4 + wid;
    if (row >= n) return;
    float s0 = 0.f, s1 = 0.f;
    const float2* Wsv = (const float2*)Ws;
    for (int k = lane; k < IND; k += 64) {
        float xv = x[(size_t)row * IND + k];
        float2 w = Wsv[k];
        s0 = fmaf(xv, w.x, s0);
        s1 = fmaf(xv, w.y, s1);
    }
    #pragma unroll
    for (int off = 32; off; off >>= 1) {
        s0 += __shfl_xor(s0, off);
        s1 += __shfl_xor(s1, off);
    }
    if (lane == 0) ((float2*)skip)[row] = make_float2(s0 + bs[0] + b2[0], s1 + bs[1] + b2[1]);
}

// ---- layer-1 aggregate + relu + fused h2 = relu(agg+b1) @ W2 ----
// one wave per node; lane l owns channels {2l, 2l+1} (float2, coalesced 512B)
__global__ __launch_bounds__(256) void agg1_kernel(const float* __restrict__ h,
                                                   const float* __restrict__ dinv,
                                                   const int* __restrict__ row_ptr,
                                                   const int* __restrict__ col_src,
                                                   const float* __restrict__ b1,
                                                   const float* __restrict__ W2,
                                                   float* __restrict__ h2, int n) {
    int wid = threadIdx.x >> 6, lane = threadIdx.x & 63;
    int i = blockIdx.x * 4 + wid;
    if (i >= n) return;
    float di = dinv[i];
    const float2* hv = (const float2*)h;
    float2 acc;
    {   // self-loop: norm = dinv[i]^2
        float2 hs = hv[(size_t)i * 64 + lane];
        float w = di * di;
        acc.x = hs.x * w;
        acc.y = hs.y * w;
    }
    int beg = row_ptr[i], end = row_ptr[i + 1];
    for (int e = beg; e < end; ++e) {
        int s = col_src[e];
        float nrm = dinv[s] * di;
        float2 hs = hv[(size_t)s * 64 + lane];
        acc.x = fmaf(hs.x, nrm, acc.x);
        acc.y = fmaf(hs.y, nrm, acc.y);
    }
    float2 bb = ((const float2*)b1)[lane];
    float vx = fmaxf(acc.x + bb.x, 0.f);
    float vy = fmaxf(acc.y + bb.y, 0.f);
    // h2[i][j] = sum_c relu_h1[c] * W2[c][j]; W2 row-major [128][2]
    float2 w2a = ((const float2*)W2)[2 * lane];
    float2 w2b = ((const float2*)W2)[2 * lane + 1];
    float p0 = vx * w2a.x + vy * w2b.x;
    float p1 = vx * w2a.y + vy * w2b.y;
    #pragma unroll
    for (int off = 32; off; off >>= 1) {
        p0 += __shfl_xor(p0, off);
        p1 += __shfl_xor(p1, off);
    }
    if (lane == 0) ((float2*)h2)[i] = make_float2(p0, p1);
}

// ---- layer-2 aggregate + skip: thread per node (h2 is tiny, L2-resident) ----
__global__ __launch_bounds__(256) void agg2_kernel(const float* __restrict__ h2,
                                                   const float* __restrict__ dinv,
                                                   const int* __restrict__ row_ptr,
                                                   const int* __restrict__ col_src,
                                                   const float* __restrict__ skip,
                                                   float* __restrict__ out, int n) {
    int i = blockIdx.x * blockDim.x + threadIdx.x;
    if (i >= n) return;
    float di = dinv[i];
    const float2* h2v = (const float2*)h2;
    float2 self = h2v[i];
    float a0 = self.x * di * di, a1 = self.y * di * di;
    int beg = row_ptr[i], end = row_ptr[i + 1];
    for (int e = beg; e < end; ++e) {
        int s = col_src[e];
        float nrm = dinv[s] * di;
        float2 hs = h2v[s];
        a0 = fmaf(hs.x, nrm, a0);
        a1 = fmaf(hs.y, nrm, a1);
    }
    float2 sk = ((const float2*)skip)[i];
    ((float2*)out)[i] = make_float2(a0 + sk.x, a1 + sk.y);
}

extern "C" void kernel_launch(void* const* d_in, const int* in_sizes, int n_in,
                              void* d_out, int out_size, void* d_ws, size_t ws_size,
                              hipStream_t stream) {
    const float* x  = (const float*)d_in[0];
    const int*   ei = (const int*)d_in[1];  // int32 view; layout auto-detected
    const float* W1 = (const float*)d_in[2];
    const float* b1 = (const float*)d_in[3];
    const float* W2 = (const float*)d_in[4];
    const float* b2 = (const float*)d_in[5];
    const float* Ws = (const float*)d_in[6];
    const float* bs = (const float*)d_in[7];
    float* out = (float*)d_out;

    const int n = in_sizes[0] / IND;        // 100000
    const int E = in_sizes[1] / 2;          // 1600000 (elements, dtype-agnostic)

    // workspace layout (256B aligned)
    char* ws = (char*)d_ws;
    size_t off = 0;
    auto alloc = [&](size_t bytes) { void* p = ws + off; off += (bytes + 255) & ~(size_t)255; return p; };
    int*   cnt     = (int*)alloc((size_t)n * 4);
    float* dinv    = (float*)alloc((size_t)n * 4);
    int*   row_ptr = (int*)alloc((size_t)(n + 1) * 4);
    int*   cursor  = (int*)alloc((size_t)n * 4);
    int*   bsum    = (int*)alloc(64 * 4);
    int*   flag    = (int*)alloc(256);
    int*   col_src = (int*)alloc((size_t)E * 4);
    float* h       = (float*)alloc((size_t)n * HID * 4);
    float* h2      = (float*)alloc((size_t)n * 2 * 4);
    float* skip    = (float*)alloc((size_t)n * 2 * 4);
    (void)ws_size;

    const int scanG = (n + 2047) / 2048;    // 49

    hipMemsetAsync(cnt, 0, (size_t)n * 4, stream);
    detect_kernel<<<1, 256, 0, stream>>>(ei, flag);
    count_kernel<<<(E + 255) / 256, 256, 0, stream>>>(ei, flag, cnt, E);
    dinv_kernel<<<(n + 255) / 256, 256, 0, stream>>>(cnt, dinv, n);
    scan1_kernel<<<scanG, 256, 0, stream>>>(cnt, row_ptr, bsum, n);
    scan2_kernel<<<1, 64, 0, stream>>>(bsum, scanG);
    scan3_kernel<<<(n + 255) / 256, 256, 0, stream>>>(row_ptr, bsum, cursor, n, E);
    fill_kernel<<<(E + 255) / 256, 256, 0, stream>>>(ei, flag, cursor, col_src, E);

    gemm1_kernel<<<(n + RB - 1) / RB, 128, 0, stream>>>(x, W1, h);
    skip_kernel<<<(n + 3) / 4, 256, 0, stream>>>(x, Ws, bs, b2, skip, n);
    agg1_kernel<<<(n + 3) / 4, 256, 0, stream>>>(h, dinv, row_ptr, col_src, b1, W2, h2, n);
    agg2_kernel<<<(n + 255) / 256, 256, 0, stream>>>(h2, dinv, row_ptr, col_src, skip, out, n);
}

// Round 2
// 447.808 us; speedup vs baseline: 1.2414x; 1.2414x over previous
//
#include <hip/hip_runtime.h>
#include <hip/hip_bf16.h>

// SkipGCN: out = gcn(relu(gcn(x,W1,b1)),W2,b2) + x@Ws + bs
// N=100000 nodes, E=1600000 edges, in=165, hid=128, out=2, fp32 in/out.
//
// R2 changes vs R1:
//  - h stored as bf16 (halves agg1 gather traffic 870->435 MB logical)
//  - agg1 edge loop unrolled x4 (more outstanding gathers; was latency-bound
//    at 19% VALUBusy / 2.4 TB/s)
//  - skip (x@Ws) fused into gemm1 (saves one 66 MB pass over x + a launch)
//  - dinv folded into scan1 (saves a launch)

#define NN 100000
#define EE 1600000
#define IND 165
#define HID 128

__device__ __forceinline__ unsigned short f2bf(float f) {
    unsigned u = __float_as_uint(f);
    unsigned r = (u + 0x7FFF + ((u >> 16) & 1)) >> 16;  // RNE
    return (unsigned short)r;
}
__device__ __forceinline__ float bf_lo(unsigned u) { return __uint_as_float(u << 16); }
__device__ __forceinline__ float bf_hi(unsigned u) { return __uint_as_float(u & 0xFFFF0000u); }

__global__ void detect_kernel(const int* e32, int* flag) {
    // int64 edges => every high 32-bit word is 0 (ids < 2^31).
    __shared__ int nz;
    if (threadIdx.x == 0) nz = 0;
    __syncthreads();
    if (e32[2 * threadIdx.x + 1] != 0) atomicOr(&nz, 1);
    __syncthreads();
    if (threadIdx.x == 0) flag[0] = (nz == 0) ? 1 : 0;  // 1 => int64 layout
}

__global__ void count_kernel(const int* e32, const int* flag, int* cnt, int E) {
    int e = blockIdx.x * blockDim.x + threadIdx.x;
    if (e >= E) return;
    int f = flag[0];
    int dst = f ? e32[2 * (E + e)] : e32[E + e];
    atomicAdd(&cnt[dst], 1);
}

// ---- exclusive scan over cnt[n] -> pref[n]; also emits dinv = rsqrt(1+cnt) ----
__global__ __launch_bounds__(256) void scan1_kernel(const int* cnt, int* pref, int* bsum,
                                                    float* dinv, int n) {
    __shared__ int sdata[256];
    int base = blockIdx.x * 2048 + threadIdx.x * 8;
    int v[8];
    int s = 0;
    #pragma unroll
    for (int j = 0; j < 8; ++j) {
        int idx = base + j;
        int t = (idx < n) ? cnt[idx] : 0;
        if (idx < n) dinv[idx] = rsqrtf(1.0f + (float)t);
        v[j] = s;
        s += t;
    }
    sdata[threadIdx.x] = s;
    __syncthreads();
    for (int off = 1; off < 256; off <<= 1) {
        int t = (threadIdx.x >= off) ? sdata[threadIdx.x - off] : 0;
        __syncthreads();
        sdata[threadIdx.x] += t;
        __syncthreads();
    }
    int excl = (threadIdx.x == 0) ? 0 : sdata[threadIdx.x - 1];
    if (threadIdx.x == 255) bsum[blockIdx.x] = sdata[255];
    #pragma unroll
    for (int j = 0; j < 8; ++j) {
        int idx = base + j;
        if (idx < n) pref[idx] = excl + v[j];
    }
}

__global__ void scan2_kernel(int* bsum, int g) {
    if (threadIdx.x == 0) {
        int run = 0;
        for (int j = 0; j < g; ++j) { int t = bsum[j]; bsum[j] = run; run += t; }
    }
}

__global__ void scan3_kernel(int* pref, const int* bsum, int* cursor, int n, int total) {
    int i = blockIdx.x * blockDim.x + threadIdx.x;
    if (i < n) {
        int v = pref[i] + bsum[i >> 11];
        pref[i] = v;
        cursor[i] = v;
    }
    if (i == 0) pref[n] = total;
}

__global__ void fill_kernel(const int* e32, const int* flag, int* cursor, int* col_src, int E) {
    int e = blockIdx.x * blockDim.x + threadIdx.x;
    if (e >= E) return;
    int f = flag[0];
    int src = f ? e32[2 * e] : e32[e];
    int dst = f ? e32[2 * (E + e)] : e32[E + e];
    int p = atomicAdd(&cursor[dst], 1);
    col_src[p] = src;
}

// ---- h(bf16) = x @ W1, fused skip = x @ Ws + bs + b2 ----
// 8 rows/block, 128 threads (thread = output channel)
#define RB 8
__global__ __launch_bounds__(128) void gemm1_kernel(const float* __restrict__ x,
                                                    const float* __restrict__ W1,
                                                    const float* __restrict__ Ws,
                                                    const float* __restrict__ bs,
                                                    const float* __restrict__ b2,
                                                    unsigned* __restrict__ hb,
                                                    float* __restrict__ skip) {
    __shared__ float xs[RB * IND];
    __shared__ unsigned short hs[RB * HID];
    __shared__ float sred[RB * 16 * 2];
    int row0 = blockIdx.x * RB;
    const float* xg = x + (size_t)row0 * IND;
    for (int t = threadIdx.x; t < RB * IND; t += 128) xs[t] = xg[t];
    __syncthreads();
    int c = threadIdx.x;
    float acc[RB];
    #pragma unroll
    for (int r = 0; r < RB; ++r) acc[r] = 0.f;
    for (int k = 0; k < IND; ++k) {
        float w = W1[k * HID + c];
        #pragma unroll
        for (int r = 0; r < RB; ++r) acc[r] = fmaf(xs[r * IND + k], w, acc[r]);
    }
    #pragma unroll
    for (int r = 0; r < RB; ++r) hs[r * HID + c] = f2bf(acc[r]);

    // skip: 16 threads per row, k strided by 16 over 165
    {
        int r = threadIdx.x >> 4, j = threadIdx.x & 15;
        float s0 = 0.f, s1 = 0.f;
        const float2* Wsv = (const float2*)Ws;
        for (int k = j; k < IND; k += 16) {
            float xv = xs[r * IND + k];
            float2 w = Wsv[k];
            s0 = fmaf(xv, w.x, s0);
            s1 = fmaf(xv, w.y, s1);
        }
        sred[(r * 16 + j) * 2 + 0] = s0;
        sred[(r * 16 + j) * 2 + 1] = s1;
    }
    __syncthreads();
    // write h: 8 rows x 64 uints contiguous = 512 uints
    {
        const unsigned* hsu = (const unsigned*)hs;
        unsigned* hg = hb + (size_t)row0 * (HID / 2);
        #pragma unroll
        for (int t = threadIdx.x; t < RB * HID / 2; t += 128) hg[t] = hsu[t];
    }
    // reduce skip partials: threads 0..7 each fold 16
    if (threadIdx.x < RB) {
        int r = threadIdx.x;
        float s0 = 0.f, s1 = 0.f;
        #pragma unroll
        for (int j = 0; j < 16; ++j) {
            s0 += sred[(r * 16 + j) * 2 + 0];
            s1 += sred[(r * 16 + j) * 2 + 1];
        }
        ((float2*)skip)[row0 + r] = make_float2(s0 + bs[0] + b2[0], s1 + bs[1] + b2[1]);
    }
}

// ---- layer-1 aggregate (bf16 h) + relu + fused h2 = relu(agg+b1) @ W2 ----
// one wave per node; lane l owns channels {2l, 2l+1} packed in one uint
__global__ __launch_bounds__(256) void agg1_kernel(const unsigned* __restrict__ hb,
                                                   const float* __restrict__ dinv,
                                                   const int* __restrict__ row_ptr,
                                                   const int* __restrict__ col_src,
                                                   const float* __restrict__ b1,
                                                   const float* __restrict__ W2,
                                                   float* __restrict__ h2, int n) {
    int wid = threadIdx.x >> 6, lane = threadIdx.x & 63;
    int i = blockIdx.x * 4 + wid;
    if (i >= n) return;
    float di = dinv[i];
    float ax, ay;
    {   // self-loop: norm = dinv[i]^2
        unsigned u = hb[(size_t)i * 64 + lane];
        float w = di * di;
        ax = bf_lo(u) * w;
        ay = bf_hi(u) * w;
    }
    int e = row_ptr[i], end = row_ptr[i + 1];
    for (; e + 4 <= end; e += 4) {
        int s0 = col_src[e], s1 = col_src[e + 1], s2 = col_src[e + 2], s3 = col_src[e + 3];
        float n0 = dinv[s0] * di, n1 = dinv[s1] * di, n2 = dinv[s2] * di, n3 = dinv[s3] * di;
        unsigned u0 = hb[(size_t)s0 * 64 + lane];
        unsigned u1 = hb[(size_t)s1 * 64 + lane];
        unsigned u2 = hb[(size_t)s2 * 64 + lane];
        unsigned u3 = hb[(size_t)s3 * 64 + lane];
        ax = fmaf(bf_lo(u0), n0, ax); ay = fmaf(bf_hi(u0), n0, ay);
        ax = fmaf(bf_lo(u1), n1, ax); ay = fmaf(bf_hi(u1), n1, ay);
        ax = fmaf(bf_lo(u2), n2, ax); ay = fmaf(bf_hi(u2), n2, ay);
        ax = fmaf(bf_lo(u3), n3, ax); ay = fmaf(bf_hi(u3), n3, ay);
    }
    for (; e < end; ++e) {
        int s = col_src[e];
        float nrm = dinv[s] * di;
        unsigned u = hb[(size_t)s * 64 + lane];
        ax = fmaf(bf_lo(u), nrm, ax);
        ay = fmaf(bf_hi(u), nrm, ay);
    }
    float2 bb = ((const float2*)b1)[lane];
    float vx = fmaxf(ax + bb.x, 0.f);
    float vy = fmaxf(ay + bb.y, 0.f);
    float2 w2a = ((const float2*)W2)[2 * lane];
    float2 w2b = ((const float2*)W2)[2 * lane + 1];
    float p0 = vx * w2a.x + vy * w2b.x;
    float p1 = vx * w2a.y + vy * w2b.y;
    #pragma unroll
    for (int off = 32; off; off >>= 1) {
        p0 += __shfl_xor(p0, off);
        p1 += __shfl_xor(p1, off);
    }
    if (lane == 0) ((float2*)h2)[i] = make_float2(p0, p1);
}

// ---- layer-2 aggregate + skip: thread per node (h2 tiny, L2-resident) ----
__global__ __launch_bounds__(256) void agg2_kernel(const float* __restrict__ h2,
                                                   const float* __restrict__ dinv,
                                                   const int* __restrict__ row_ptr,
                                                   const int* __restrict__ col_src,
                                                   const float* __restrict__ skip,
                                                   float* __restrict__ out, int n) {
    int i = blockIdx.x * blockDim.x + threadIdx.x;
    if (i >= n) return;
    float di = dinv[i];
    const float2* h2v = (const float2*)h2;
    float2 self = h2v[i];
    float a0 = self.x * di * di, a1 = self.y * di * di;
    int beg = row_ptr[i], end = row_ptr[i + 1];
    for (int e = beg; e < end; ++e) {
        int s = col_src[e];
        float nrm = dinv[s] * di;
        float2 hs = h2v[s];
        a0 = fmaf(hs.x, nrm, a0);
        a1 = fmaf(hs.y, nrm, a1);
    }
    float2 sk = ((const float2*)skip)[i];
    ((float2*)out)[i] = make_float2(a0 + sk.x, a1 + sk.y);
}

extern "C" void kernel_launch(void* const* d_in, const int* in_sizes, int n_in,
                              void* d_out, int out_size, void* d_ws, size_t ws_size,
                              hipStream_t stream) {
    const float* x  = (const float*)d_in[0];
    const int*   ei = (const int*)d_in[1];  // int32 view; layout auto-detected
    const float* W1 = (const float*)d_in[2];
    const float* b1 = (const float*)d_in[3];
    const float* W2 = (const float*)d_in[4];
    const float* b2 = (const float*)d_in[5];
    const float* Ws = (const float*)d_in[6];
    const float* bs = (const float*)d_in[7];
    float* out = (float*)d_out;

    const int n = in_sizes[0] / IND;        // 100000
    const int E = in_sizes[1] / 2;          // 1600000

    char* ws = (char*)d_ws;
    size_t off = 0;
    auto alloc = [&](size_t bytes) { void* p = ws + off; off += (bytes + 255) & ~(size_t)255; return p; };
    int*      cnt     = (int*)alloc((size_t)n * 4);
    float*    dinv    = (float*)alloc((size_t)n * 4);
    int*      row_ptr = (int*)alloc((size_t)(n + 1) * 4);
    int*      cursor  = (int*)alloc((size_t)n * 4);
    int*      bsum    = (int*)alloc(64 * 4);
    int*      flag    = (int*)alloc(256);
    int*      col_src = (int*)alloc((size_t)E * 4);
    unsigned* hb      = (unsigned*)alloc((size_t)n * (HID / 2) * 4);  // bf16 h
    float*    h2      = (float*)alloc((size_t)n * 2 * 4);
    float*    skip    = (float*)alloc((size_t)n * 2 * 4);
    (void)ws_size;

    const int scanG = (n + 2047) / 2048;

    hipMemsetAsync(cnt, 0, (size_t)n * 4, stream);
    detect_kernel<<<1, 256, 0, stream>>>(ei, flag);
    count_kernel<<<(E + 255) / 256, 256, 0, stream>>>(ei, flag, cnt, E);
    scan1_kernel<<<scanG, 256, 0, stream>>>(cnt, row_ptr, bsum, dinv, n);
    scan2_kernel<<<1, 64, 0, stream>>>(bsum, scanG);
    scan3_kernel<<<(n + 255) / 256, 256, 0, stream>>>(row_ptr, bsum, cursor, n, E);
    fill_kernel<<<(E + 255) / 256, 256, 0, stream>>>(ei, flag, cursor, col_src, E);

    gemm1_kernel<<<(n + RB - 1) / RB, 128, 0, stream>>>(x, W1, Ws, bs, b2, hb, skip);
    agg1_kernel<<<(n + 3) / 4, 256, 0, stream>>>(hb, dinv, row_ptr, col_src, b1, W2, h2, n);
    agg2_kernel<<<(n + 255) / 256, 256, 0, stream>>>(h2, dinv, row_ptr, col_src, skip, out, n);
}

// Round 3
// 416.546 us; speedup vs baseline: 1.3345x; 1.0751x over previous
//
#include <hip/hip_runtime.h>
#include <hip/hip_bf16.h>

// SkipGCN: out = gcn(relu(gcn(x,W1,b1)),W2,b2) + x@Ws + bs
// N=100000, E=1600000, in=165, hid=128, out=2, fp32 in/out.
//
// R3 changes vs R2:
//  - gemm1 moved to MFMA (16x16x32 bf16): was VALU-issue-bound at 152us
//    (62% VALUBusy, 8 LDS reads per 8 FMAs). 64 rows x 128 cols per block,
//    4 waves, K padded 165->192 (6 steps). x staged bf16 in LDS (stride 200
//    bf16 = conflict-free frag reads), W1^T bf16 in ws (L2-resident).
//  - skip still fused in gemm1, reads x f32 from global (L1-warm).

#define NN 100000
#define EE 1600000
#define IND 165
#define HID 128
#define KP 192          // padded K for MFMA
#define XSS 200         // LDS row stride in bf16 elems (100 dwords)

typedef __attribute__((ext_vector_type(8))) short short8v;
typedef __attribute__((ext_vector_type(4))) float float4v;

__device__ __forceinline__ unsigned short f2bf(float f) {
    unsigned u = __float_as_uint(f);
    unsigned r = (u + 0x7FFF + ((u >> 16) & 1)) >> 16;  // RNE
    return (unsigned short)r;
}
__device__ __forceinline__ float bf_lo(unsigned u) { return __uint_as_float(u << 16); }
__device__ __forceinline__ float bf_hi(unsigned u) { return __uint_as_float(u & 0xFFFF0000u); }

__global__ void detect_kernel(const int* e32, int* flag) {
    __shared__ int nz;
    if (threadIdx.x == 0) nz = 0;
    __syncthreads();
    if (e32[2 * threadIdx.x + 1] != 0) atomicOr(&nz, 1);
    __syncthreads();
    if (threadIdx.x == 0) flag[0] = (nz == 0) ? 1 : 0;  // 1 => int64 layout
}

__global__ void count_kernel(const int* e32, const int* flag, int* cnt, int E) {
    int e = blockIdx.x * blockDim.x + threadIdx.x;
    if (e >= E) return;
    int f = flag[0];
    int dst = f ? e32[2 * (E + e)] : e32[E + e];
    atomicAdd(&cnt[dst], 1);
}

// ---- exclusive scan over cnt -> pref; also dinv = rsqrt(1+cnt) ----
__global__ __launch_bounds__(256) void scan1_kernel(const int* cnt, int* pref, int* bsum,
                                                    float* dinv, int n) {
    __shared__ int sdata[256];
    int base = blockIdx.x * 2048 + threadIdx.x * 8;
    int v[8];
    int s = 0;
    #pragma unroll
    for (int j = 0; j < 8; ++j) {
        int idx = base + j;
        int t = (idx < n) ? cnt[idx] : 0;
        if (idx < n) dinv[idx] = rsqrtf(1.0f + (float)t);
        v[j] = s;
        s += t;
    }
    sdata[threadIdx.x] = s;
    __syncthreads();
    for (int off = 1; off < 256; off <<= 1) {
        int t = (threadIdx.x >= off) ? sdata[threadIdx.x - off] : 0;
        __syncthreads();
        sdata[threadIdx.x] += t;
        __syncthreads();
    }
    int excl = (threadIdx.x == 0) ? 0 : sdata[threadIdx.x - 1];
    if (threadIdx.x == 255) bsum[blockIdx.x] = sdata[255];
    #pragma unroll
    for (int j = 0; j < 8; ++j) {
        int idx = base + j;
        if (idx < n) pref[idx] = excl + v[j];
    }
}

__global__ void scan2_kernel(int* bsum, int g) {
    if (threadIdx.x == 0) {
        int run = 0;
        for (int j = 0; j < g; ++j) { int t = bsum[j]; bsum[j] = run; run += t; }
    }
}

__global__ void scan3_kernel(int* pref, const int* bsum, int* cursor, int n, int total) {
    int i = blockIdx.x * blockDim.x + threadIdx.x;
    if (i < n) {
        int v = pref[i] + bsum[i >> 11];
        pref[i] = v;
        cursor[i] = v;
    }
    if (i == 0) pref[n] = total;
}

__global__ void fill_kernel(const int* e32, const int* flag, int* cursor, int* col_src, int E) {
    int e = blockIdx.x * blockDim.x + threadIdx.x;
    if (e >= E) return;
    int f = flag[0];
    int src = f ? e32[2 * e] : e32[e];
    int dst = f ? e32[2 * (E + e)] : e32[E + e];
    int p = atomicAdd(&cursor[dst], 1);
    col_src[p] = src;
}

// ---- W1 [165][128] f32 -> W1^T [128][192] bf16 (k-padded with zeros) ----
__global__ void w1t_kernel(const float* __restrict__ W1, unsigned short* __restrict__ w1t) {
    int t = blockIdx.x * 256 + threadIdx.x;
    if (t >= HID * KP) return;
    int nn = t / KP, k = t - nn * KP;
    w1t[t] = (k < IND) ? f2bf(W1[k * HID + nn]) : (unsigned short)0;
}

// ---- MFMA gemm1: hb(bf16) = x @ W1, fused skip = x @ Ws + bs + b2 ----
// 64 rows x 128 cols per block, 256 threads (4 waves x 16 rows).
__global__ __launch_bounds__(256) void gemm1_kernel(const float* __restrict__ x,
                                                    const unsigned short* __restrict__ w1t,
                                                    const float* __restrict__ Ws,
                                                    const float* __restrict__ bs,
                                                    const float* __restrict__ b2,
                                                    unsigned short* __restrict__ hb,
                                                    float* __restrict__ skip, int n) {
    __shared__ unsigned short xs[64 * XSS];
    const int row0 = blockIdx.x * 64;

    // zero pad region k in [160,200)
    for (int t = threadIdx.x; t < 64 * 40; t += 256) {
        int r = t / 40, k = 160 + (t - (t / 40) * 40);
        xs[r * XSS + k] = 0;
    }
    // stage x rows (bf16)
    for (int t = threadIdx.x; t < 64 * IND; t += 256) {
        int r = t / IND, k = t - r * IND;
        int row = row0 + r;
        float v = (row < n) ? x[(size_t)row * IND + k] : 0.f;
        xs[r * XSS + k] = f2bf(v);
    }
    __syncthreads();

    const int wave = threadIdx.x >> 6, lane = threadIdx.x & 63;
    const int l15 = lane & 15, lk = (lane >> 4) * 8;

    float4v acc[8];
    #pragma unroll
    for (int nt = 0; nt < 8; ++nt) acc[nt] = (float4v){0.f, 0.f, 0.f, 0.f};

    const unsigned short* arow = xs + (wave * 16 + l15) * XSS;
    #pragma unroll
    for (int ks = 0; ks < 6; ++ks) {
        int k0 = ks * 32 + lk;
        short8v a = *(const short8v*)(arow + k0);
        #pragma unroll
        for (int nt = 0; nt < 8; ++nt) {
            short8v b = *(const short8v*)(w1t + (size_t)(nt * 16 + l15) * KP + k0);
            acc[nt] = __builtin_amdgcn_mfma_f32_16x16x32_bf16(a, b, acc[nt], 0, 0, 0);
        }
    }

    // epilogue: C layout col=lane&15, row=(lane>>4)*4+r
    const int orow0 = row0 + wave * 16 + (lane >> 4) * 4;
    #pragma unroll
    for (int nt = 0; nt < 8; ++nt) {
        int col = nt * 16 + l15;
        #pragma unroll
        for (int r = 0; r < 4; ++r) {
            int row = orow0 + r;
            if (row < n) hb[(size_t)row * HID + col] = f2bf(acc[nt][r]);
        }
    }

    // skip: 4 threads per row, x re-read f32 from global (L1-warm)
    {
        int r = threadIdx.x >> 2, j = threadIdx.x & 3;
        int row = row0 + r;
        float s0 = 0.f, s1 = 0.f;
        if (row < n) {
            const float* xr = x + (size_t)row * IND;
            const float2* Wsv = (const float2*)Ws;
            for (int k = j; k < IND; k += 4) {
                float xv = xr[k];
                float2 w = Wsv[k];
                s0 = fmaf(xv, w.x, s0);
                s1 = fmaf(xv, w.y, s1);
            }
        }
        s0 += __shfl_xor(s0, 1); s0 += __shfl_xor(s0, 2);
        s1 += __shfl_xor(s1, 1); s1 += __shfl_xor(s1, 2);
        if (j == 0 && row < n)
            ((float2*)skip)[row] = make_float2(s0 + bs[0] + b2[0], s1 + bs[1] + b2[1]);
    }
}

// ---- layer-1 aggregate (bf16 h) + relu + fused h2 = relu(agg+b1) @ W2 ----
__global__ __launch_bounds__(256) void agg1_kernel(const unsigned* __restrict__ hbu,
                                                   const float* __restrict__ dinv,
                                                   const int* __restrict__ row_ptr,
                                                   const int* __restrict__ col_src,
                                                   const float* __restrict__ b1,
                                                   const float* __restrict__ W2,
                                                   float* __restrict__ h2, int n) {
    int wid = threadIdx.x >> 6, lane = threadIdx.x & 63;
    int i = blockIdx.x * 4 + wid;
    if (i >= n) return;
    float di = dinv[i];
    float ax, ay;
    {
        unsigned u = hbu[(size_t)i * 64 + lane];
        float w = di * di;
        ax = bf_lo(u) * w;
        ay = bf_hi(u) * w;
    }
    int e = row_ptr[i], end = row_ptr[i + 1];
    for (; e + 4 <= end; e += 4) {
        int s0 = col_src[e], s1 = col_src[e + 1], s2 = col_src[e + 2], s3 = col_src[e + 3];
        float n0 = dinv[s0] * di, n1 = dinv[s1] * di, n2 = dinv[s2] * di, n3 = dinv[s3] * di;
        unsigned u0 = hbu[(size_t)s0 * 64 + lane];
        unsigned u1 = hbu[(size_t)s1 * 64 + lane];
        unsigned u2 = hbu[(size_t)s2 * 64 + lane];
        unsigned u3 = hbu[(size_t)s3 * 64 + lane];
        ax = fmaf(bf_lo(u0), n0, ax); ay = fmaf(bf_hi(u0), n0, ay);
        ax = fmaf(bf_lo(u1), n1, ax); ay = fmaf(bf_hi(u1), n1, ay);
        ax = fmaf(bf_lo(u2), n2, ax); ay = fmaf(bf_hi(u2), n2, ay);
        ax = fmaf(bf_lo(u3), n3, ax); ay = fmaf(bf_hi(u3), n3, ay);
    }
    for (; e < end; ++e) {
        int s = col_src[e];
        float nrm = dinv[s] * di;
        unsigned u = hbu[(size_t)s * 64 + lane];
        ax = fmaf(bf_lo(u), nrm, ax);
        ay = fmaf(bf_hi(u), nrm, ay);
    }
    float2 bb = ((const float2*)b1)[lane];
    float vx = fmaxf(ax + bb.x, 0.f);
    float vy = fmaxf(ay + bb.y, 0.f);
    float2 w2a = ((const float2*)W2)[2 * lane];
    float2 w2b = ((const float2*)W2)[2 * lane + 1];
    float p0 = vx * w2a.x + vy * w2b.x;
    float p1 = vx * w2a.y + vy * w2b.y;
    #pragma unroll
    for (int off = 32; off; off >>= 1) {
        p0 += __shfl_xor(p0, off);
        p1 += __shfl_xor(p1, off);
    }
    if (lane == 0) ((float2*)h2)[i] = make_float2(p0, p1);
}

// ---- layer-2 aggregate + skip ----
__global__ __launch_bounds__(256) void agg2_kernel(const float* __restrict__ h2,
                                                   const float* __restrict__ dinv,
                                                   const int* __restrict__ row_ptr,
                                                   const int* __restrict__ col_src,
                                                   const float* __restrict__ skip,
                                                   float* __restrict__ out, int n) {
    int i = blockIdx.x * blockDim.x + threadIdx.x;
    if (i >= n) return;
    float di = dinv[i];
    const float2* h2v = (const float2*)h2;
    float2 self = h2v[i];
    float a0 = self.x * di * di, a1 = self.y * di * di;
    int beg = row_ptr[i], end = row_ptr[i + 1];
    for (int e = beg; e < end; ++e) {
        int s = col_src[e];
        float nrm = dinv[s] * di;
        float2 hs = h2v[s];
        a0 = fmaf(hs.x, nrm, a0);
        a1 = fmaf(hs.y, nrm, a1);
    }
    float2 sk = ((const float2*)skip)[i];
    ((float2*)out)[i] = make_float2(a0 + sk.x, a1 + sk.y);
}

extern "C" void kernel_launch(void* const* d_in, const int* in_sizes, int n_in,
                              void* d_out, int out_size, void* d_ws, size_t ws_size,
                              hipStream_t stream) {
    const float* x  = (const float*)d_in[0];
    const int*   ei = (const int*)d_in[1];
    const float* W1 = (const float*)d_in[2];
    const float* b1 = (const float*)d_in[3];
    const float* W2 = (const float*)d_in[4];
    const float* b2 = (const float*)d_in[5];
    const float* Ws = (const float*)d_in[6];
    const float* bs = (const float*)d_in[7];
    float* out = (float*)d_out;

    const int n = in_sizes[0] / IND;
    const int E = in_sizes[1] / 2;

    char* ws = (char*)d_ws;
    size_t off = 0;
    auto alloc = [&](size_t bytes) { void* p = ws + off; off += (bytes + 255) & ~(size_t)255; return p; };
    int*            cnt     = (int*)alloc((size_t)n * 4);
    float*          dinv    = (float*)alloc((size_t)n * 4);
    int*            row_ptr = (int*)alloc((size_t)(n + 1) * 4);
    int*            cursor  = (int*)alloc((size_t)n * 4);
    int*            bsum    = (int*)alloc(64 * 4);
    int*            flag    = (int*)alloc(256);
    int*            col_src = (int*)alloc((size_t)E * 4);
    unsigned short* hb      = (unsigned short*)alloc((size_t)n * HID * 2);
    float*          h2      = (float*)alloc((size_t)n * 2 * 4);
    float*          skip    = (float*)alloc((size_t)n * 2 * 4);
    unsigned short* w1t     = (unsigned short*)alloc((size_t)HID * KP * 2);
    (void)ws_size;

    const int scanG = (n + 2047) / 2048;

    hipMemsetAsync(cnt, 0, (size_t)n * 4, stream);
    detect_kernel<<<1, 256, 0, stream>>>(ei, flag);
    w1t_kernel<<<(HID * KP + 255) / 256, 256, 0, stream>>>(W1, w1t);
    count_kernel<<<(E + 255) / 256, 256, 0, stream>>>(ei, flag, cnt, E);
    scan1_kernel<<<scanG, 256, 0, stream>>>(cnt, row_ptr, bsum, dinv, n);
    scan2_kernel<<<1, 64, 0, stream>>>(bsum, scanG);
    scan3_kernel<<<(n + 255) / 256, 256, 0, stream>>>(row_ptr, bsum, cursor, n, E);
    fill_kernel<<<(E + 255) / 256, 256, 0, stream>>>(ei, flag, cursor, col_src, E);

    gemm1_kernel<<<(n + 63) / 64, 256, 0, stream>>>(x, w1t, Ws, bs, b2, hb, skip, n);
    agg1_kernel<<<(n + 3) / 4, 256, 0, stream>>>((const unsigned*)hb, dinv, row_ptr, col_src, b1, W2, h2, n);
    agg2_kernel<<<(n + 255) / 256, 256, 0, stream>>>(h2, dinv, row_ptr, col_src, skip, out, n);
}

// Round 4
// 256.315 us; speedup vs baseline: 2.1688x; 1.6251x over previous
//
#include <hip/hip_runtime.h>
#include <hip/hip_bf16.h>

// SkipGCN: out = gcn(relu(gcn(x,W1,b1)),W2,b2) + x@Ws + bs
// N=100000, E=1600000, in=165, hid=128, out=2, fp32 in/out.
//
// R4 changes vs R3:
//  - CSR build rewritten: count+scan123+fill (5 kernels, ~190us, fill had 16x
//    write amplification: 105MB WRITE for 6.4MB payload) replaced by
//    partition->bscan->buildB. Scatters confined to block-local bucket
//    regions so L2 lines go fully dirty before eviction.
//  - deg/dinv/row_ptr now derived from bucket records (count_kernel deleted).
//  - gemm1 (MFMA), agg1, agg2 unchanged from R3.

#define IND 165
#define HID 128
#define KP 192          // padded K for MFMA
#define XSS 200         // LDS row stride in bf16 elems
#define SLAB 8192       // per-bucket slab capacity (avg fill ~4092, 64 sigma)
#define MAXNB 512       // max buckets (supports n up to 131072)

typedef __attribute__((ext_vector_type(8))) short short8v;
typedef __attribute__((ext_vector_type(4))) float float4v;

__device__ __forceinline__ unsigned short f2bf(float f) {
    unsigned u = __float_as_uint(f);
    unsigned r = (u + 0x7FFF + ((u >> 16) & 1)) >> 16;  // RNE
    return (unsigned short)r;
}
__device__ __forceinline__ float bf_lo(unsigned u) { return __uint_as_float(u << 16); }
__device__ __forceinline__ float bf_hi(unsigned u) { return __uint_as_float(u & 0xFFFF0000u); }

__global__ void detect_kernel(const int* e32, int* flag) {
    __shared__ int nz;
    if (threadIdx.x == 0) nz = 0;
    __syncthreads();
    if (e32[2 * threadIdx.x + 1] != 0) atomicOr(&nz, 1);
    __syncthreads();
    if (threadIdx.x == 0) flag[0] = (nz == 0) ? 1 : 0;  // 1 => int64 layout
}

// ---- partition: edges -> per-bucket slabs of records (dstLow<<24 | src) ----
// 8192 edges/block, 32/thread (fully unrolled -> registers, rule #20).
__global__ __launch_bounds__(256) void partition_kernel(const int* __restrict__ e32,
                                                        const int* __restrict__ flag,
                                                        int* __restrict__ bucket_len,
                                                        unsigned* __restrict__ slab,
                                                        int E, int NB) {
    __shared__ unsigned hist[MAXNB];
    __shared__ unsigned runbase[MAXNB];
    __shared__ unsigned cnt2[MAXNB];
    for (int t = threadIdx.x; t < NB; t += 256) { hist[t] = 0; cnt2[t] = 0; }
    __syncthreads();
    const int f = flag[0];
    const int base = blockIdx.x * 8192;
    unsigned rec[32];
    unsigned bk[32];
    #pragma unroll
    for (int j = 0; j < 32; ++j) {
        int e = base + j * 256 + threadIdx.x;
        if (e < E) {
            int src, dst;
            if (f) {
                int2 s2 = ((const int2*)e32)[e];
                int2 d2 = ((const int2*)e32)[E + e];
                src = s2.x; dst = d2.x;
            } else {
                src = e32[e];
                dst = e32[E + e];
            }
            unsigned b = (unsigned)dst >> 8;
            rec[j] = ((unsigned)(dst & 255) << 24) | (unsigned)src;
            bk[j] = b;
            atomicAdd(&hist[b], 1u);
        } else {
            bk[j] = 0xFFFFFFFFu;
            rec[j] = 0;
        }
    }
    __syncthreads();
    for (int t = threadIdx.x; t < NB; t += 256) {
        unsigned h = hist[t];
        runbase[t] = h ? (unsigned)atomicAdd(&bucket_len[t], (int)h) : 0u;
    }
    __syncthreads();
    #pragma unroll
    for (int j = 0; j < 32; ++j) {
        unsigned b = bk[j];
        if (b != 0xFFFFFFFFu) {
            unsigned p = runbase[b] + atomicAdd(&cnt2[b], 1u);
            if (p < SLAB) slab[(size_t)b * SLAB + p] = rec[j];
        }
    }
}

// ---- bscan: exclusive scan of bucket lengths -> bucket_base[NB+1], row_ptr[n] ----
__global__ __launch_bounds__(256) void bscan_kernel(const int* __restrict__ bucket_len,
                                                    int* __restrict__ bucket_base,
                                                    int* __restrict__ row_ptr, int n, int NB) {
    __shared__ int sa[MAXNB], sb[MAXNB];
    int t = threadIdx.x;
    for (int i = t; i < MAXNB; i += 256) sa[i] = (i < NB) ? min(bucket_len[i], SLAB) : 0;
    __syncthreads();
    int* s = sa; int* d = sb;
    for (int off = 1; off < MAXNB; off <<= 1) {
        for (int i = t; i < MAXNB; i += 256) d[i] = s[i] + ((i >= off) ? s[i - off] : 0);
        __syncthreads();
        int* tmp = s; s = d; d = tmp;
    }
    // s = inclusive scan
    for (int i = t; i <= NB; i += 256) bucket_base[i] = (i == 0) ? 0 : s[i - 1];
    if (t == 0) row_ptr[n] = s[NB - 1];
}

// ---- buildB: block per bucket -> deg/dinv/row_ptr + col_src scatter ----
__global__ __launch_bounds__(256) void buildb_kernel(const unsigned* __restrict__ slab,
                                                     const int* __restrict__ bucket_len,
                                                     const int* __restrict__ bucket_base,
                                                     int* __restrict__ row_ptr,
                                                     float* __restrict__ dinv,
                                                     int* __restrict__ col_src, int n) {
    __shared__ unsigned deg[256];
    __shared__ unsigned sa[256], sb[256];
    __shared__ unsigned cur[256];
    const int b = blockIdx.x;
    int len = min(bucket_len[b], SLAB);
    const int bb = bucket_base[b];
    const unsigned* recs = slab + (size_t)b * SLAB;
    const int d0 = b << 8;
    const int t = threadIdx.x;
    deg[t] = 0;
    __syncthreads();
    for (int i = t; i < len; i += 256) atomicAdd(&deg[recs[i] >> 24], 1u);
    __syncthreads();
    unsigned dv = deg[t];
    sa[t] = dv;
    __syncthreads();
    unsigned* s = sa; unsigned* d = sb;
    for (int off = 1; off < 256; off <<= 1) {
        d[t] = s[t] + ((t >= off) ? s[t - off] : 0);
        __syncthreads();
        unsigned* tmp = s; s = d; d = tmp;
    }
    unsigned excl = s[t] - dv;
    if (d0 + t < n) {
        dinv[d0 + t] = rsqrtf(1.0f + (float)dv);
        row_ptr[d0 + t] = bb + (int)excl;
    }
    cur[t] = excl;
    __syncthreads();
    for (int i = t; i < len; i += 256) {
        unsigned r = recs[i];
        unsigned p = (unsigned)bb + atomicAdd(&cur[r >> 24], 1u);
        col_src[p] = (int)(r & 0xFFFFFFu);
    }
}

// ---- W1 [165][128] f32 -> W1^T [128][192] bf16 (k-padded) ----
__global__ void w1t_kernel(const float* __restrict__ W1, unsigned short* __restrict__ w1t) {
    int t = blockIdx.x * 256 + threadIdx.x;
    if (t >= HID * KP) return;
    int nn = t / KP, k = t - nn * KP;
    w1t[t] = (k < IND) ? f2bf(W1[k * HID + nn]) : (unsigned short)0;
}

// ---- MFMA gemm1: hb(bf16) = x @ W1, fused skip = x @ Ws + bs + b2 ----
__global__ __launch_bounds__(256) void gemm1_kernel(const float* __restrict__ x,
                                                    const unsigned short* __restrict__ w1t,
                                                    const float* __restrict__ Ws,
                                                    const float* __restrict__ bs,
                                                    const float* __restrict__ b2,
                                                    unsigned short* __restrict__ hb,
                                                    float* __restrict__ skip, int n) {
    __shared__ unsigned short xs[64 * XSS];
    const int row0 = blockIdx.x * 64;

    for (int t = threadIdx.x; t < 64 * 40; t += 256) {
        int r = t / 40, k = 160 + (t - (t / 40) * 40);
        xs[r * XSS + k] = 0;
    }
    for (int t = threadIdx.x; t < 64 * IND; t += 256) {
        int r = t / IND, k = t - r * IND;
        int row = row0 + r;
        float v = (row < n) ? x[(size_t)row * IND + k] : 0.f;
        xs[r * XSS + k] = f2bf(v);
    }
    __syncthreads();

    const int wave = threadIdx.x >> 6, lane = threadIdx.x & 63;
    const int l15 = lane & 15, lk = (lane >> 4) * 8;

    float4v acc[8];
    #pragma unroll
    for (int nt = 0; nt < 8; ++nt) acc[nt] = (float4v){0.f, 0.f, 0.f, 0.f};

    const unsigned short* arow = xs + (wave * 16 + l15) * XSS;
    #pragma unroll
    for (int ks = 0; ks < 6; ++ks) {
        int k0 = ks * 32 + lk;
        short8v a = *(const short8v*)(arow + k0);
        #pragma unroll
        for (int nt = 0; nt < 8; ++nt) {
            short8v b = *(const short8v*)(w1t + (size_t)(nt * 16 + l15) * KP + k0);
            acc[nt] = __builtin_amdgcn_mfma_f32_16x16x32_bf16(a, b, acc[nt], 0, 0, 0);
        }
    }

    const int orow0 = row0 + wave * 16 + (lane >> 4) * 4;
    #pragma unroll
    for (int nt = 0; nt < 8; ++nt) {
        int col = nt * 16 + l15;
        #pragma unroll
        for (int r = 0; r < 4; ++r) {
            int row = orow0 + r;
            if (row < n) hb[(size_t)row * HID + col] = f2bf(acc[nt][r]);
        }
    }

    {
        int r = threadIdx.x >> 2, j = threadIdx.x & 3;
        int row = row0 + r;
        float s0 = 0.f, s1 = 0.f;
        if (row < n) {
            const float* xr = x + (size_t)row * IND;
            const float2* Wsv = (const float2*)Ws;
            for (int k = j; k < IND; k += 4) {
                float xv = xr[k];
                float2 w = Wsv[k];
                s0 = fmaf(xv, w.x, s0);
                s1 = fmaf(xv, w.y, s1);
            }
        }
        s0 += __shfl_xor(s0, 1); s0 += __shfl_xor(s0, 2);
        s1 += __shfl_xor(s1, 1); s1 += __shfl_xor(s1, 2);
        if (j == 0 && row < n)
            ((float2*)skip)[row] = make_float2(s0 + bs[0] + b2[0], s1 + bs[1] + b2[1]);
    }
}

// ---- layer-1 aggregate (bf16 h) + relu + fused h2 = relu(agg+b1) @ W2 ----
__global__ __launch_bounds__(256) void agg1_kernel(const unsigned* __restrict__ hbu,
                                                   const float* __restrict__ dinv,
                                                   const int* __restrict__ row_ptr,
                                                   const int* __restrict__ col_src,
                                                   const float* __restrict__ b1,
                                                   const float* __restrict__ W2,
                                                   float* __restrict__ h2, int n) {
    int wid = threadIdx.x >> 6, lane = threadIdx.x & 63;
    int i = blockIdx.x * 4 + wid;
    if (i >= n) return;
    float di = dinv[i];
    float ax, ay;
    {
        unsigned u = hbu[(size_t)i * 64 + lane];
        float w = di * di;
        ax = bf_lo(u) * w;
        ay = bf_hi(u) * w;
    }
    int e = row_ptr[i], end = row_ptr[i + 1];
    for (; e + 4 <= end; e += 4) {
        int s0 = col_src[e], s1 = col_src[e + 1], s2 = col_src[e + 2], s3 = col_src[e + 3];
        float n0 = dinv[s0] * di, n1 = dinv[s1] * di, n2 = dinv[s2] * di, n3 = dinv[s3] * di;
        unsigned u0 = hbu[(size_t)s0 * 64 + lane];
        unsigned u1 = hbu[(size_t)s1 * 64 + lane];
        unsigned u2 = hbu[(size_t)s2 * 64 + lane];
        unsigned u3 = hbu[(size_t)s3 * 64 + lane];
        ax = fmaf(bf_lo(u0), n0, ax); ay = fmaf(bf_hi(u0), n0, ay);
        ax = fmaf(bf_lo(u1), n1, ax); ay = fmaf(bf_hi(u1), n1, ay);
        ax = fmaf(bf_lo(u2), n2, ax); ay = fmaf(bf_hi(u2), n2, ay);
        ax = fmaf(bf_lo(u3), n3, ax); ay = fmaf(bf_hi(u3), n3, ay);
    }
    for (; e < end; ++e) {
        int s = col_src[e];
        float nrm = dinv[s] * di;
        unsigned u = hbu[(size_t)s * 64 + lane];
        ax = fmaf(bf_lo(u), nrm, ax);
        ay = fmaf(bf_hi(u), nrm, ay);
    }
    float2 bb = ((const float2*)b1)[lane];
    float vx = fmaxf(ax + bb.x, 0.f);
    float vy = fmaxf(ay + bb.y, 0.f);
    float2 w2a = ((const float2*)W2)[2 * lane];
    float2 w2b = ((const float2*)W2)[2 * lane + 1];
    float p0 = vx * w2a.x + vy * w2b.x;
    float p1 = vx * w2a.y + vy * w2b.y;
    #pragma unroll
    for (int off = 32; off; off >>= 1) {
        p0 += __shfl_xor(p0, off);
        p1 += __shfl_xor(p1, off);
    }
    if (lane == 0) ((float2*)h2)[i] = make_float2(p0, p1);
}

// ---- layer-2 aggregate + skip ----
__global__ __launch_bounds__(256) void agg2_kernel(const float* __restrict__ h2,
                                                   const float* __restrict__ dinv,
                                                   const int* __restrict__ row_ptr,
                                                   const int* __restrict__ col_src,
                                                   const float* __restrict__ skip,
                                                   float* __restrict__ out, int n) {
    int i = blockIdx.x * blockDim.x + threadIdx.x;
    if (i >= n) return;
    float di = dinv[i];
    const float2* h2v = (const float2*)h2;
    float2 self = h2v[i];
    float a0 = self.x * di * di, a1 = self.y * di * di;
    int beg = row_ptr[i], end = row_ptr[i + 1];
    for (int e = beg; e < end; ++e) {
        int s = col_src[e];
        float nrm = dinv[s] * di;
        float2 hs = h2v[s];
        a0 = fmaf(hs.x, nrm, a0);
        a1 = fmaf(hs.y, nrm, a1);
    }
    float2 sk = ((const float2*)skip)[i];
    ((float2*)out)[i] = make_float2(a0 + sk.x, a1 + sk.y);
}

extern "C" void kernel_launch(void* const* d_in, const int* in_sizes, int n_in,
                              void* d_out, int out_size, void* d_ws, size_t ws_size,
                              hipStream_t stream) {
    const float* x  = (const float*)d_in[0];
    const int*   ei = (const int*)d_in[1];
    const float* W1 = (const float*)d_in[2];
    const float* b1 = (const float*)d_in[3];
    const float* W2 = (const float*)d_in[4];
    const float* b2 = (const float*)d_in[5];
    const float* Ws = (const float*)d_in[6];
    const float* bs = (const float*)d_in[7];
    float* out = (float*)d_out;

    const int n = in_sizes[0] / IND;        // 100000
    const int E = in_sizes[1] / 2;          // 1600000
    const int NB = (n + 255) >> 8;          // 391 buckets of 256 nodes

    char* ws = (char*)d_ws;
    size_t off = 0;
    auto alloc = [&](size_t bytes) { void* p = ws + off; off += (bytes + 255) & ~(size_t)255; return p; };
    int*            flag        = (int*)alloc(256);
    int*            bucket_len  = (int*)alloc((size_t)(MAXNB + 1) * 4);
    int*            bucket_base = (int*)alloc((size_t)(MAXNB + 1) * 4);
    unsigned*       slab        = (unsigned*)alloc((size_t)NB * SLAB * 4);
    int*            row_ptr     = (int*)alloc((size_t)(n + 1) * 4);
    float*          dinv        = (float*)alloc((size_t)n * 4);
    int*            col_src     = (int*)alloc((size_t)E * 4);
    unsigned short* hb          = (unsigned short*)alloc((size_t)n * HID * 2);
    float*          h2          = (float*)alloc((size_t)n * 2 * 4);
    float*          skip        = (float*)alloc((size_t)n * 2 * 4);
    unsigned short* w1t         = (unsigned short*)alloc((size_t)HID * KP * 2);
    (void)ws_size;

    hipMemsetAsync(bucket_len, 0, (size_t)NB * 4, stream);
    detect_kernel<<<1, 256, 0, stream>>>(ei, flag);
    w1t_kernel<<<(HID * KP + 255) / 256, 256, 0, stream>>>(W1, w1t);
    partition_kernel<<<(E + 8191) / 8192, 256, 0, stream>>>(ei, flag, bucket_len, slab, E, NB);
    bscan_kernel<<<1, 256, 0, stream>>>(bucket_len, bucket_base, row_ptr, n, NB);
    buildb_kernel<<<NB, 256, 0, stream>>>(slab, bucket_len, bucket_base, row_ptr, dinv, col_src, n);

    gemm1_kernel<<<(n + 63) / 64, 256, 0, stream>>>(x, w1t, Ws, bs, b2, hb, skip, n);
    agg1_kernel<<<(n + 3) / 4, 256, 0, stream>>>((const unsigned*)hb, dinv, row_ptr, col_src, b1, W2, h2, n);
    agg2_kernel<<<(n + 255) / 256, 256, 0, stream>>>(h2, dinv, row_ptr, col_src, skip, out, n);
}